// Round 1
// baseline (195.746 us; speedup 1.0000x reference)
//
#include <hip/hip_runtime.h>

#define L_IN   4000
#define CIN    512
#define KSZ    16
#define LOUT   31992   // 8 * 3999
#define NQ     3999    // valid q: 0..3998
#define QPB    256     // q positions per block
#define CPB    256     // ci per block (2-way ci split over blockIdx.z)
#define RST    1088    // reduction region stride: 64 lanes * 17 floats

// Grid (16 q-tiles, 16 b, 2 ci-halves) = 512 blocks of 512 threads (8 waves)
// -> 2 independent blocks/CU (same 16 waves/CU as before, but two barrier
// domains: one block's main loop hides the other's reduction/barriers).
// Wave w owns ci [cih*256 + w*32, +32); thread owns 4 CONTIGUOUS q
// (qb = q0 + 4*lane) -> per (wave,ci) the x-load stays one 1 KB contiguous
// float4 burst. Main loop is explicitly software-pipelined: distance-2
// global prefetch (x + halo), distance-1 LDS weight prefetch, so next-iter
// loads are issued before each 64-FMA burst instead of batch-issue/drain.
// Each ci-half atomically accumulates its partial outputs (native fp32
// global atomic; 2 commutative addends -> order-independent result), with
// the output zero-initialized by a hipMemsetAsync in the captured stream.
__global__ __launch_bounds__(512, 4)
void dereverb_kernel(const float* __restrict__ x,
                     const float* __restrict__ t60s,
                     const float* __restrict__ kw,
                     float* __restrict__ out)
{
    __shared__ float lds[4 * RST];   // 17 KB: 16 KB weight stage, reused as 4 regions

    const int b    = blockIdx.y;
    const int q0   = blockIdx.x * QPB;
    const int cih  = blockIdx.z;
    const int tid  = threadIdx.x;
    const int lane = tid & 63;
    const int wave = tid >> 6;       // 0..7

    // Per-sample kernel index (uniform): jnp.round = RNE = rintf.
    float t60 = t60s[b & 7];
    int kidx = (int)rintf(t60 * 100.0f) - 10;
    kidx = __builtin_amdgcn_readfirstlane(kidx);
    const float4* wsrc = (const float4*)(kw + ((size_t)kidx * CIN + cih * CPB) * KSZ);

    // Stage this half's 256x16 weights: 1024 float4 / 512 threads = 2 each.
    ((float4*)lds)[tid]       = wsrc[tid];
    ((float4*)lds)[tid + 512] = wsrc[tid + 512];
    __syncthreads();

    // Lane's q base; clamps keep all loads inside the current row.
    const int qb  = q0 + 4 * lane;
    const int qbl = qb < 3996 ? qb : 3996;          // 16B-aligned float4 base
    const int qan = (qb + 4) < NQ ? (qb + 4) : NQ;  // halo x[q+4]

    const float* xr = x + ((size_t)b * CIN + cih * CPB + wave * 32) * L_IN;
    const float* xp = xr + qbl;
    const float* xq = xr + qan;
    const float4* wl = (const float4*)(lds + wave * 32 * KSZ);

    float acc[4][8];
    #pragma unroll
    for (int qi = 0; qi < 4; ++qi)
        #pragma unroll
        for (int r = 0; r < 8; ++r) acc[qi][r] = 0.0f;

#define FMA_BODY(A, AN, W0, W1, W2, W3) do {                        \
        const float xl[4] = {(A).x, (A).y, (A).z, (A).w};           \
        const float xh[4] = {(A).y, (A).z, (A).w, (AN)};            \
        const float wa[8] = {(W0).x,(W0).y,(W0).z,(W0).w,           \
                             (W1).x,(W1).y,(W1).z,(W1).w};          \
        const float wb[8] = {(W2).x,(W2).y,(W2).z,(W2).w,           \
                             (W3).x,(W3).y,(W3).z,(W3).w};          \
        _Pragma("unroll")                                           \
        for (int qi = 0; qi < 4; ++qi)                              \
            _Pragma("unroll")                                       \
            for (int r = 0; r < 8; ++r) {                           \
                acc[qi][r] = fmaf(xh[qi], wa[r], acc[qi][r]);       \
                acc[qi][r] = fmaf(xl[qi], wb[r], acc[qi][r]);       \
            }                                                       \
    } while (0)

    // Software-pipelined main loop over the wave's 32 ci rows.
    float4 a0 = *(const float4*)xp;
    float  n0 = *xq;
    float4 a1 = *(const float4*)(xp + L_IN);
    float  n1 = *(xq + L_IN);
    float4 w0 = wl[0], w1 = wl[1], w2 = wl[2], w3 = wl[3];

    #pragma unroll 2
    for (int ci = 0; ci < 30; ++ci) {
        float4 a2 = *(const float4*)(xp + 2 * L_IN);   // global prefetch, d=2
        float  n2 = *(xq + 2 * L_IN);
        float4 u0 = wl[4], u1 = wl[5], u2 = wl[6], u3 = wl[7];  // LDS prefetch, d=1
        FMA_BODY(a0, n0, w0, w1, w2, w3);
        a0 = a1; n0 = n1; a1 = a2; n1 = n2;
        w0 = u0; w1 = u1; w2 = u2; w3 = u3;
        xp += L_IN; xq += L_IN; wl += 4;
    }
    {   // ci = 30: last weight prefetch; x(31) already in a1/n1
        float4 u0 = wl[4], u1 = wl[5], u2 = wl[6], u3 = wl[7];
        FMA_BODY(a0, n0, w0, w1, w2, w3);
        a0 = a1; n0 = n1;
        w0 = u0; w1 = u1; w2 = u2; w3 = u3;
    }
    FMA_BODY(a0, n0, w0, w1, w2, w3);   // ci = 31

    // Zero contributions from invalid q (> 3998) / clamped lanes.
    #pragma unroll
    for (int qi = 0; qi < 4; ++qi)
        if (qb + qi > NQ - 1)
            #pragma unroll
            for (int r = 0; r < 8; ++r) acc[qi][r] = 0.0f;

    // 8-wave reduction in two passes over qi-halves (qi = 2p+qih).
    // Region w layout: addr = w*RST + lane*17 + qih*8 + r (17-padded chunks,
    // bank-balanced). Epilogue sums 4 regions and atomically accumulates
    // this ci-half's partials into the zero-initialized output.
    const size_t obase = (size_t)b * LOUT + (size_t)q0 * 8;
    #pragma unroll
    for (int p = 0; p < 2; ++p) {
        __syncthreads();                 // weights / previous pass reads done
        if (wave >= 4) {                 // waves 4..7 store region (wave-4)
            float* rp = lds + (wave - 4) * RST + lane * 17;
            #pragma unroll
            for (int qih = 0; qih < 2; ++qih)
                #pragma unroll
                for (int r = 0; r < 8; ++r)
                    rp[qih * 8 + r] = acc[2 * p + qih][r];
        }
        __syncthreads();
        if (wave < 4) {                  // waves 0..3 fold into region wave
            float* rp = lds + wave * RST + lane * 17;
            #pragma unroll
            for (int qih = 0; qih < 2; ++qih)
                #pragma unroll
                for (int r = 0; r < 8; ++r)
                    rp[qih * 8 + r] += acc[2 * p + qih][r];
        }
        __syncthreads();
        // Pass p covers, per compute-lane kc, outputs tl = 32*kc + 16p + j.
        // 1024 outputs/pass, 512 threads -> 2 each (kc = k and k+32).
        const int k = tid >> 4, j = tid & 15;
        #pragma unroll
        for (int kk = 0; kk < 2; ++kk) {
            const int kc = k + 32 * kk;
            const int tl = 32 * kc + 16 * p + j;
            if (q0 * 8 + tl < LOUT) {    // only the last q-tile trims
                float s = lds[0 * RST + kc * 17 + j]
                        + lds[1 * RST + kc * 17 + j]
                        + lds[2 * RST + kc * 17 + j]
                        + lds[3 * RST + kc * 17 + j];
                unsafeAtomicAdd(&out[obase + tl], s);   // global_atomic_add_f32
            }
        }
    }
#undef FMA_BODY
}

extern "C" void kernel_launch(void* const* d_in, const int* in_sizes, int n_in,
                              void* d_out, int out_size, void* d_ws, size_t ws_size,
                              hipStream_t stream) {
    const float* x    = (const float*)d_in[0];   // (16, 512, 4000)
    const float* t60s = (const float*)d_in[1];   // (8,)
    const float* kw   = (const float*)d_in[2];   // (41, 512, 1, 16)
    float* out = (float*)d_out;                  // (16, 1, 31992)

    // Zero-init for the two ci-half atomic accumulations (graph-capturable).
    hipMemsetAsync(d_out, 0, out_size, stream);

    dim3 grid((NQ + QPB - 1) / QPB, 16, 2);      // (16, 16, 2) = 512 blocks
    dereverb_kernel<<<grid, 512, 0, stream>>>(x, t60s, kw, out);
}